// Round 13
// baseline (194.755 us; speedup 1.0000x reference)
//
#include <hip/hip_runtime.h>

// DenseLayerWithComplexNeurons: out = per-cell-type-MLP( x @ W^T + b )
// M = B*S = 8192, K = DIN = 1024, N = A*DOUT = 4096, DOUT = 1024
// T = 4 cell types, G = 256 neurons/type, A = 4, H = 8.
//
// FUSED KERNEL = Round 10/15 configuration (session optimum, 94.5 us,
// reproduced). Session ledger of closed levers (counter evidence):
//  R4-7,11 counted-vmcnt/raw-barrier pipelines: all >= 112 us (compiler's
//    __syncthreads scheduling wins; guide m131-m141 confirmed here).
//  R8/R12/R13 occupancy: register-structural (220 regs/wave) and
//    latency-not-occupancy-hideable (37% occ, flat) -- closed.
//  R14 B-from-global: conflicts -67% as predicted, wall +7us -- LDS pipe
//    was never the limiter. Closed.
//  R9/R10 stage->compute->sync dbuf + lane-local epilogue: the real wins.
// R16 (this round): fused untouched. Conversion rebuilt as two max-ILP
//  streaming kernels (16 floats/thread, 4x dwordx4 ILP, no branch):
//  decisive probe of the ~60-95 us total-vs-fused gap. If total is flat,
//  gap is harness-fixed and the session terminates at this source.

typedef __bf16 bf16x8 __attribute__((ext_vector_type(8)));
typedef float f32x4 __attribute__((ext_vector_type(4)));
typedef float f32x16 __attribute__((ext_vector_type(16)));

#define BM 256
#define BN 128
#define BK 32
#define KDIM 1024
#define NT 32                        // K / BK
#define ABUF 16384                   // A bytes per buffer (256 rows x 32 k x 2B)
#define BUFB 24576                   // per-buffer bytes: A 16K + B 8K

// ---- conversion kernels: pure streaming, 16 floats/thread ----

__global__ __launch_bounds__(256) void cvt_x_kernel(
    const float* __restrict__ x, __bf16* __restrict__ xb) {
    const size_t i = (size_t)blockIdx.x * 256 + threadIdx.x;   // 0..524287
    const f32x4* p = (const f32x4*)x + 4 * i;
    const f32x4 a = p[0], b = p[1], c = p[2], d = p[3];
    bf16x8 o0, o1;
    o0[0] = (__bf16)a[0]; o0[1] = (__bf16)a[1]; o0[2] = (__bf16)a[2]; o0[3] = (__bf16)a[3];
    o0[4] = (__bf16)b[0]; o0[5] = (__bf16)b[1]; o0[6] = (__bf16)b[2]; o0[7] = (__bf16)b[3];
    o1[0] = (__bf16)c[0]; o1[1] = (__bf16)c[1]; o1[2] = (__bf16)c[2]; o1[3] = (__bf16)c[3];
    o1[4] = (__bf16)d[0]; o1[5] = (__bf16)d[1]; o1[6] = (__bf16)d[2]; o1[7] = (__bf16)d[3];
    bf16x8* q = (bf16x8*)xb + 2 * i;
    q[0] = o0; q[1] = o1;
}

__global__ __launch_bounds__(256) void cvt_w_kernel(
    const float* __restrict__ w, __bf16* __restrict__ wb) {
    const size_t i = (size_t)blockIdx.x * 256 + threadIdx.x;   // 0..262143
    // Two consecutive 8-elem units j=2i, 2i+1. c8=2i&127 is even (<127), so
    // both units share row r -> same permuted row rn, contiguous dest.
    const int j  = 2 * (int)i;
    const int r  = j >> 7;
    const int c8 = j & 127;
    // W row permutation (R10-verified): r = 4q+a -> 128*(q>>5) + 32a + (q&31)
    const int q  = r >> 2;
    const int a  = r & 3;
    const int rn = ((q >> 5) << 7) + (a << 5) + (q & 31);
    const int jd = (rn << 7) + c8;
    const f32x4* p = (const f32x4*)w + 4 * i;
    const f32x4 va = p[0], vb = p[1], vc = p[2], vd = p[3];
    bf16x8 o0, o1;
    o0[0] = (__bf16)va[0]; o0[1] = (__bf16)va[1]; o0[2] = (__bf16)va[2]; o0[3] = (__bf16)va[3];
    o0[4] = (__bf16)vb[0]; o0[5] = (__bf16)vb[1]; o0[6] = (__bf16)vb[2]; o0[7] = (__bf16)vb[3];
    o1[0] = (__bf16)vc[0]; o1[1] = (__bf16)vc[1]; o1[2] = (__bf16)vc[2]; o1[3] = (__bf16)vc[3];
    o1[4] = (__bf16)vd[0]; o1[5] = (__bf16)vd[1]; o1[6] = (__bf16)vd[2]; o1[7] = (__bf16)vd[3];
    bf16x8* dq = (bf16x8*)wb + jd;
    dq[0] = o0; dq[1] = o1;
}

__global__ __launch_bounds__(256, 2) void fused_gemm_mlp_kernel(
    const __bf16* __restrict__ Ag,   // [8192][1024] bf16 (x)
    const __bf16* __restrict__ Bg,   // [4096][1024] bf16 (perm'd weight, B^T layout)
    const float* __restrict__ bias,  // [4096] (original order)
    const float* __restrict__ cw1,   // [4][4][8]
    const float* __restrict__ cb1,   // [4][8]
    const float* __restrict__ cw2,   // [4][8]
    const float* __restrict__ cb2,   // [4]
    float* __restrict__ out)         // [8192][1024]
{
    __shared__ __align__(16) unsigned char raw[2 * BUFB];   // 49152 B

    const int tid  = threadIdx.x;
    const int wave = tid >> 6;       // 0..3 = m quarter (64 rows each)
    const int lane = tid & 63;
    const int wm = wave;
    const int bn0 = blockIdx.x * BN; // n offset in [0,4096)
    const int bm0 = blockIdx.y * BM; // m offset in [0,8192)

    f32x16 acc[2][4] = {};           // 2 m-tiles x 4 a-subtiles of 32x32

    // ---- staging lane mapping (row-pair physical rows; verified R9/R10) ----
    // 1KB DMA chunk = 16 rows (8 row-pairs x 128B). Lane i writes byte 16*i:
    // q_loc=i>>3, slot=i&7; source: s_log=slot^q_loc, row=2q_loc+(s_log>>2),
    // col16=s_log&3. Global (R,c) lands at chunk*1024 + ((R>>1)&7)*128 +
    // (((R&1)*4+c)^((R>>1)&7))*16 == fragment address below.
    const int qloc = lane >> 3;
    const int slog = (lane & 7) ^ qloc;
    const int arow = 2 * qloc + (slog >> 2);
    const int acol = (slog & 3) * 8;

    // ---- fragment LDS byte addresses (buffer-relative; verified R10) ----
    // MFMA 32x32x16: row = lane&31, k = kh*16 + (lane>>5)*8 + i.
    // A row = wm*64 + mi*32 + lr5 -> wm*4096 + mi*2048 + lrh*128 + slot
    // B row = a*32 + lr5          -> ABUF + a*2048 + lrh*128 + slot
    const int lr5 = lane & 31;
    const int lk2 = lane >> 5;   // 0..1
    const int lrh = lr5 >> 1;    // 0..15
    const int lp  = lr5 & 1;
    int a_addr[2], b_addr[2];
#pragma unroll
    for (int kh = 0; kh < 2; ++kh) {
        const int slot = (((lp * 4) + (kh * 2 + lk2)) ^ (lrh & 7)) * 16;
        a_addr[kh] = wm * 4096 + lrh * 128 + slot;
        b_addr[kh] = ABUF + lrh * 128 + slot;
    }
    const char* sb = (const char*)raw;

    // ---- stage one BK=32 tile t into buffer (t&1): 24 chunks, 6 per wave ----
    auto stage = [&](int t) {
        const int bb = (t & 1) * BUFB;
        const int k0 = t * BK;
#pragma unroll
        for (int c = 0; c < 4; ++c) {          // A: 16 chunks of 16 rows
            const int ch = wave + c * 4;
            const __bf16* g = Ag + (size_t)(bm0 + ch * 16 + arow) * KDIM + k0 + acol;
            __builtin_amdgcn_global_load_lds(
                (__attribute__((address_space(1))) void*)g,
                (__attribute__((address_space(3))) void*)&raw[bb + ch * 1024],
                16, 0, 0);
        }
#pragma unroll
        for (int c = 0; c < 2; ++c) {          // B: 8 chunks of 16 rows
            const int ch = wave + c * 4;
            const __bf16* g = Bg + (size_t)(bn0 + ch * 16 + arow) * KDIM + k0 + acol;
            __builtin_amdgcn_global_load_lds(
                (__attribute__((address_space(1))) void*)g,
                (__attribute__((address_space(3))) void*)&raw[bb + ABUF + ch * 1024],
                16, 0, 0);
        }
    };

    // ---- prologue: tile 0 staged and drained ----
    stage(0);
    __syncthreads();

    // ---- main loop: stage(t+1) -> compute(t) -> barrier (verified R9/R10) ----
    // Safety under plain __syncthreads semantics:
    //  - stage(t+1) writes nbuf; last reads of nbuf (compute t-1) were
    //    lgkm-drained at the barrier ending iter t-1.  (WAR ok)
    //  - compute(t) reads cbuf; every wave's stage(t) DMA drained by the
    //    implicit vmcnt(0) of the barrier ending iter t-1.  (RAW ok)
    //  - this iter's barrier drains stage(t+1) AFTER compute(t) -> DMA
    //    latency hidden under 12 ds_read_b128 + 16 MFMA.
    for (int t = 0; t < NT; ++t) {
        if (t + 1 < NT) stage(t + 1);

        const int cb = (t & 1) * BUFB;
#pragma unroll
        for (int kh = 0; kh < 2; ++kh) {
            bf16x8 af[2], bfr[4];
#pragma unroll
            for (int mi = 0; mi < 2; ++mi)
                af[mi] = *(const bf16x8*)(sb + cb + a_addr[kh] + mi * 2048);
#pragma unroll
            for (int a = 0; a < 4; ++a)
                bfr[a] = *(const bf16x8*)(sb + cb + b_addr[kh] + a * 2048);
#pragma unroll
            for (int mi = 0; mi < 2; ++mi)
#pragma unroll
                for (int a = 0; a < 4; ++a)
                    acc[mi][a] = __builtin_amdgcn_mfma_f32_32x32x16_bf16(
                        af[mi], bfr[a], acc[mi][a], 0, 0, 0);
        }
        __syncthreads();
    }

    // ---- epilogue: fully lane-local per-neuron MLP (verified R10) ----
    // Lane (lr5) owns neuron q = bn0/4 + lr5; acc[mi][a][g] = z(row, 4q+a)
    // with row = wm*64 + mi*32 + (g&3) + 8*(g>>2) + 4*lk2.
    const int tct = bn0 >> 10;  // cell type, block-uniform
    float w1[32], b1[8], w2[8];
#pragma unroll
    for (int i = 0; i < 32; ++i) w1[i] = cw1[tct * 32 + i];
#pragma unroll
    for (int i = 0; i < 8; ++i) { b1[i] = cb1[tct * 8 + i]; w2[i] = cw2[tct * 8 + i]; }
    const float b2 = cb2[tct];

    const f32x4 bz = *(const f32x4*)&bias[bn0 + 4 * lr5];   // components a=0..3

    const float L2E2 = 2.885390081777927f;  // 2*log2(e)
    float* outp = out + (size_t)(bm0 + wm * 64 + 4 * lk2) * 1024 + (bn0 >> 2) + lr5;

#pragma unroll
    for (int mi = 0; mi < 2; ++mi) {
#pragma unroll
        for (int g = 0; g < 16; ++g) {
            const float z0 = acc[mi][0][g] + bz[0];
            const float z1 = acc[mi][1][g] + bz[1];
            const float z2 = acc[mi][2][g] + bz[2];
            const float z3 = acc[mi][3][g] + bz[3];
            float o = 0.f;
#pragma unroll
            for (int hh = 0; hh < 8; ++hh) {
                float pre = z0 * w1[0 * 8 + hh] + z1 * w1[1 * 8 + hh]
                          + z2 * w1[2 * 8 + hh] + z3 * w1[3 * 8 + hh] + b1[hh];
                float e = __builtin_amdgcn_exp2f(pre * L2E2);        // e^(2*pre)
                float th = 1.0f - 2.0f * __builtin_amdgcn_rcpf(e + 1.0f);
                o += th * w2[hh];
            }
            o += b2;
            const int row = mi * 32 + (g & 3) + 8 * (g >> 2);  // + wm*64 + 4*lk2 in outp
            outp[(size_t)row * 1024] = o;
        }
    }
}

extern "C" void kernel_launch(void* const* d_in, const int* in_sizes, int n_in,
                              void* d_out, int out_size, void* d_ws, size_t ws_size,
                              hipStream_t stream) {
    const float* x    = (const float*)d_in[0];
    const float* w    = (const float*)d_in[1];
    const float* bias = (const float*)d_in[2];
    const float* cw1  = (const float*)d_in[3];
    const float* cb1  = (const float*)d_in[4];
    const float* cw2  = (const float*)d_in[5];
    const float* cb2  = (const float*)d_in[6];
    float* out = (float*)d_out;

    __bf16* xb = (__bf16*)d_ws;                       // 8192*1024 bf16 = 16 MB
    __bf16* wb = xb + (size_t)8192 * 1024;            // 4096*1024 bf16 = 8 MB

    cvt_x_kernel<<<2048, 256, 0, stream>>>(x, xb);    // 8M floats, 16/thread
    cvt_w_kernel<<<1024, 256, 0, stream>>>(w, wb);    // 4M floats, 16/thread

    dim3 grid(4096 / BN, 8192 / BM);  // (32, 32)
    fused_gemm_mlp_kernel<<<grid, 256, 0, stream>>>(xb, wb, bias, cw1, cb1, cw2, cb2, out);
}